// Round 20
// baseline (746.868 us; speedup 1.0000x reference)
//
#include <hip/hip_runtime.h>

typedef unsigned short u16;
typedef unsigned int u32;
typedef __attribute__((ext_vector_type(8))) u16 u16x8;
typedef __attribute__((ext_vector_type(8))) __bf16 bf16x8;
typedef __attribute__((ext_vector_type(4))) float f32x4;

__device__ __forceinline__ float b2f(u16 u){ return __uint_as_float(((u32)u)<<16); }
__device__ __forceinline__ u16 f2b(float f){
  u32 b = __float_as_uint(f);
  return (u16)((b + 0x7fffu + ((b>>16)&1u))>>16);
}
__device__ __forceinline__ void gload16(const void* g, void* l){
  __builtin_amdgcn_global_load_lds((__attribute__((address_space(1))) void*)g,
                                   (__attribute__((address_space(3))) void*)l, 16, 0, 0);
}
__device__ __forceinline__ float wred_max(float v){
#pragma unroll
  for (int o=32;o>0;o>>=1) v = fmaxf(v, __shfl_xor(v,o));
  return v;
}
__device__ __forceinline__ float wred_sum(float v){
#pragma unroll
  for (int o=32;o>0;o>>=1) v += __shfl_xor(v,o);
  return v;
}

// out1 column order (set by W1T permutation in k_pre):
//   [0,512)   : vq (original order)   -- computed ONLY for unmasked rows
//   512+h*128 : head h's vk(64)|vv(64) -- all rows (agent attn needs every key)

// ---- fused preprocessing: cast x | weight transposes | agent qkv | row list ----
__global__ void k_pre(const float* __restrict__ x, const float* __restrict__ wvq,
                      const float* __restrict__ wvkv, const float* __restrict__ wout,
                      const float* __restrict__ waqkv, const float* __restrict__ mask,
                      u16* __restrict__ xb, u16* __restrict__ W1T,
                      u16* __restrict__ WoutT, float* __restrict__ aqkv,
                      u32* __restrict__ rowlist, u32* __restrict__ cnt){
  const int bid = blockIdx.x, tid = threadIdx.x;
  if (bid < 2048){
    const int stride = 2048*256;
    for (int i = bid*256 + tid; i < 8030720; i += stride){
      const float4* p = (const float4*)(x + (size_t)i*8);
      float4 a = p[0], b = p[1];
      u16x8 o;
      o[0]=f2b(a.x); o[1]=f2b(a.y); o[2]=f2b(a.z); o[3]=f2b(a.w);
      o[4]=f2b(b.x); o[5]=f2b(b.y); o[6]=f2b(b.z); o[7]=f2b(b.w);
      *(u16x8*)(xb + (size_t)i*8) = o;
    }
  } else if (bid < 6144){
    int id = (bid-2048)*256 + tid;
    if (id < 786432){
      int n = id >> 9, k = id & 511;
      float v;
      if (n < 512){
        v = wvq[k*512 + n];
      } else {
        int j = n - 512, h = j >> 7, r = j & 127;
        int c2 = (r < 64) ? (h*64 + r) : (512 + h*64 + (r - 64));   // vk | vv
        v = wvkv[k*1024 + c2];
      }
      W1T[id] = f2b(v);
    } else {
      int j = id - 786432;
      int n = j >> 9, k = j & 511;
      WoutT[j] = f2b(wout[k*512 + n]);
    }
  } else if (bid < 6384){
    int id = (bid-6144)*256 + tid;
    int bt = id / 1536, c = id % 1536;
    const float* xr = x + (size_t)bt*3137*512;
    float s = 0.f;
    for (int k=0;k<512;k++) s += xr[k]*waqkv[k*1536+c];
    aqkv[id] = s;
  } else {
    // compacted row list: wave-aggregated ballot append
    int j = (bid-6384)*256 + tid;    // [0, 125696)
    bool pred = false; u32 row = 0;
    if (j < 125440){
      int bt = j / 3136, nv = j - bt*3136;
      pred = (mask[j] != 0.f);
      row = (u32)(bt*3137 + 1 + nv);
    } else if (j < 125480){
      pred = true;                   // 40 agent rows always included
      row = (u32)((j - 125440) * 3137);
    }
    unsigned long long bal = __ballot(pred);
    const int lane = tid & 63;
    u32 base = 0;
    if (lane == 0 && bal) base = atomicAdd(cnt, (u32)__popcll(bal));
    base = __shfl(base, 0);
    if (pred){
      int pos = __popcll(bal & ((1ull << lane) - 1ull));
      rowlist[base + pos] = row;
    }
  }
}

// ======== 256x256 GEMM, 8-phase schedule (m201 port, r17/r19-verified) ========
// MODE 2: gathered rows (rowlist, M=*cntp), f32 + bias out         (GEMM2)
// MODE 3: MERGED GEMM1 -- blocks [0,NKV) = KV part (dense rows, XCD-swizzled
//   over NKV, B = BT+512*512, coff=512, NX=4); blocks [NKV,...) = VQ part
//   (gathered rows, identity map -- r18 measured: swizzle idles XCDs 4-7 on
//   prefix ranges -- B = BT, coff=0, NX=2, early-exit past cnt). KV and VQ
//   are independent (disjoint out1 cols) -> one dispatch, tail overlap.
// All per-part variables are BLOCK-UNIFORM (scalar branch; r11 lesson).
template<int MODE>
__global__ __launch_bounds__(512, 2) void k_gemm8p(
    const u16* __restrict__ A, const u16* __restrict__ BT,
    int M, int NKV, int K, int ldc,
    u16* __restrict__ Cb, float* __restrict__ Cf, const float* __restrict__ bias,
    const u32* __restrict__ rowlist, const u32* __restrict__ cntp)
{
  __shared__ __align__(16) char Ls[131072];
  char* LA = Ls;             // + d*32768 + h*16384
  char* LB = Ls + 65536;
  const int tid = threadIdx.x;
  const int wid = tid >> 6, lane = tid & 63;
  const int wm = wid >> 2, wn = wid & 3;
  int Mg, work, NX, coff;
  bool gather;
  const u16* Bp;
  if (MODE == 2){
    Mg = (int)*cntp; gather = true; Bp = BT; NX = 2; coff = 0;
    work = blockIdx.x;               // identity map (r19-verified)
    if ((work / NX) * 256 >= Mg) return;
  } else { // MODE 3
    if ((int)blockIdx.x < NKV){
      // KV part: dense, XCD-bijective swizzle (m204) over NKV blocks
      Mg = M; gather = false; Bp = BT + 512*512; NX = 4; coff = 512;
      const int q8 = NKV >> 3, r8 = NKV & 7;
      const int xc = blockIdx.x & 7, sl = blockIdx.x >> 3;
      work = (xc < r8 ? xc*(q8+1) : r8*(q8+1) + (xc-r8)*q8) + sl;
    } else {
      Mg = (int)*cntp; gather = true; Bp = BT; NX = 2; coff = 0;
      work = blockIdx.x - NKV;       // identity map
      if ((work / NX) * 256 >= Mg) return;
    }
  }
  const int m0 = (work / NX) * 256, n0 = (work % NX) * 256;
  const size_t K2 = (size_t)K * 2;
  const char* Ab = (const char*)A;
  const char* Bb = (const char*)Bp;
  size_t asrch[2], bsrch[2];
#pragma unroll
  for (int h=0; h<2; h++){
    int ra = m0 + h*128 + wid*16 + (lane & 15);
    if (ra >= Mg) ra = Mg - 1;                     // clamp partial tail
    size_t arow = gather ? (size_t)rowlist[ra] : (size_t)ra;
    asrch[h] = arow * K2 + ((lane >> 4) << 4);
    bsrch[h] = (size_t)(n0 + h*128 + wid*16 + (lane & 15)) * K2 + ((lane >> 4) << 4);
  }
  const int sd0 = wid*2048;                        // wave-uniform LDS dest base

#define STG_A(d,h,kt) { size_t ko = (size_t)(kt)*128; \
    gload16(Ab + asrch[h] + ko,      LA + (d)*32768 + (h)*16384 + sd0); \
    gload16(Ab + asrch[h] + ko + 64, LA + (d)*32768 + (h)*16384 + sd0 + 1024); }
#define STG_B(d,h,kt) { size_t ko = (size_t)(kt)*128; \
    gload16(Bb + bsrch[h] + ko,      LB + (d)*32768 + (h)*16384 + sd0); \
    gload16(Bb + bsrch[h] + ko + 64, LB + (d)*32768 + (h)*16384 + sd0 + 1024); }

  bf16x8 afr[4][2], bfr[2][2];
#define RD_A(d,QM) { const char* ab_ = LA + (d)*32768 + (QM)*16384 + wm*8192 + lane*16; \
    _Pragma("unroll") for (int fm=0; fm<4; fm++){ \
      afr[fm][0] = *(const bf16x8*)(ab_ + fm*2048); \
      afr[fm][1] = *(const bf16x8*)(ab_ + fm*2048 + 1024); } }
#define RD_B(d,QN) { const char* bb_ = LB + (d)*32768 + (QN)*16384 + wn*4096 + lane*16; \
    _Pragma("unroll") for (int fn=0; fn<2; fn++){ \
      bfr[fn][0] = *(const bf16x8*)(bb_ + fn*2048); \
      bfr[fn][1] = *(const bf16x8*)(bb_ + fn*2048 + 1024); } }

  f32x4 acc[8][4] = {};
#define MFMA16(QM,QN) { \
    _Pragma("unroll") for (int fm=0; fm<4; fm++){ \
      _Pragma("unroll") for (int fn=0; fn<2; fn++){ \
        acc[(QM)*4+fm][(QN)*2+fn] = __builtin_amdgcn_mfma_f32_16x16x32_bf16( \
            afr[fm][0], bfr[fn][0], acc[(QM)*4+fm][(QN)*2+fn], 0,0,0); \
        acc[(QM)*4+fm][(QN)*2+fn] = __builtin_amdgcn_mfma_f32_16x16x32_bf16( \
            afr[fm][1], bfr[fn][1], acc[(QM)*4+fm][(QN)*2+fn], 0,0,0); } } }

#define PH_MID(QM,QN) \
    __builtin_amdgcn_sched_barrier(0); \
    __builtin_amdgcn_s_barrier(); \
    asm volatile("s_waitcnt lgkmcnt(0)" ::: "memory"); \
    __builtin_amdgcn_sched_barrier(0); \
    __builtin_amdgcn_s_setprio(1); \
    MFMA16(QM,QN) \
    __builtin_amdgcn_s_setprio(0); \
    __builtin_amdgcn_sched_barrier(0);
#define BAR __builtin_amdgcn_s_barrier()

  const int NI = K >> 7;                           // K=512 -> 4 iterations
  STG_A(0,0,0) STG_B(0,1,0) STG_A(0,1,0) STG_B(0,0,0) STG_A(1,0,1) STG_B(1,1,1)
  asm volatile("s_waitcnt vmcnt(4)" ::: "memory");
  BAR;

  for (int it = 0; it < NI; ++it){
    const int t1 = 2*it + 1, t2 = 2*it + 2, t3 = 2*it + 3;
    const bool more = (it + 1 < NI);
    RD_A(0,0) RD_B(0,0) STG_A(1,1,t1)
    PH_MID(0,0) BAR;
    RD_B(0,1) STG_B(1,0,t1)
    PH_MID(0,1) BAR;
    RD_A(0,1) if (more){ STG_A(0,0,t2) }
    PH_MID(1,1) BAR;
    RD_B(0,0) if (more){ STG_B(0,1,t2) }
    PH_MID(1,0)
    if (more) { asm volatile("s_waitcnt vmcnt(4)" ::: "memory"); }
    else      { asm volatile("s_waitcnt vmcnt(0)" ::: "memory"); }
    BAR;
    RD_A(1,0) RD_B(1,0) if (more){ STG_A(0,1,t2) }
    PH_MID(0,0) BAR;
    RD_B(1,1) if (more){ STG_B(0,0,t2) }
    PH_MID(0,1) BAR;
    RD_A(1,1) if (more){ STG_A(1,0,t3) }
    PH_MID(1,1) BAR;
    RD_B(1,0) if (more){ STG_B(1,1,t3) }
    PH_MID(1,0)
    if (more) { asm volatile("s_waitcnt vmcnt(4)" ::: "memory"); }
    BAR;
  }
#undef STG_A
#undef STG_B
#undef RD_A
#undef RD_B
#undef MFMA16
#undef PH_MID
#undef BAR
  // epilogue: plain scalar stores (nt = 2x write amp r4; routed epilogues r11/r12)
  const bool full = (m0 + 256 <= Mg);
  if (full){
#pragma unroll
    for (int mi=0; mi<8; mi++){
      const int rb = m0 + (mi>>2)*128 + wm*64 + (mi&3)*16 + ((lane>>4)<<2);
#pragma unroll
      for (int rg=0; rg<4; rg++){
        const int r = rb + rg;
        const size_t orow = gather ? (size_t)rowlist[r] : (size_t)r;
#pragma unroll
        for (int ni=0; ni<4; ni++){
          const int col = n0 + (ni>>1)*128 + wn*32 + (ni&1)*16 + (lane&15);
          float v = acc[mi][ni][rg];
          if (MODE == 2) Cf[orow*(size_t)ldc + col] = v + bias[col];
          else           Cb[orow*(size_t)ldc + coff + col] = f2b(v);
        }
      }
    }
  } else {
#pragma unroll
    for (int mi=0; mi<8; mi++){
      const int rb = m0 + (mi>>2)*128 + wm*64 + (mi&3)*16 + ((lane>>4)<<2);
#pragma unroll
      for (int rg=0; rg<4; rg++){
        const int r = rb + rg;
        if (r < Mg){
          const size_t orow = gather ? (size_t)rowlist[r] : (size_t)r;
#pragma unroll
          for (int ni=0; ni<4; ni++){
            const int col = n0 + (ni>>1)*128 + wn*32 + (ni&1)*16 + (lane&15);
            float v = acc[mi][ni][rg];
            if (MODE == 2) Cf[orow*(size_t)ldc + col] = v + bias[col];
            else           Cb[orow*(size_t)ldc + coff + col] = f2b(v);
          }
        }
      }
    }
  }
}

// ---------------- agent attention: softmax over 15680 keys, split-K=16 ----------------
__global__ __launch_bounds__(320) void k_attn_agent(
    const u16* __restrict__ out1, const float* __restrict__ aqkv,
    float* __restrict__ pm, float* __restrict__ pl, float* __restrict__ pacc)
{
  __shared__ __align__(16) char Ksm[16384];   // 128 keys x 64 bf16, XOR-swizzled
  __shared__ __align__(16) char Vsm[16384];
  const int bid = blockIdx.x;
  const int sp = bid & 15, bh = bid >> 4, b = bh >> 3, h = bh & 7;
  const int tid = threadIdx.x, wid = tid >> 6, lane = tid & 63;
  const int q = wid;
  float qreg[64];
  {
    const float* ap = aqkv + ((size_t)(b*5+q)*1536 + h*64);
#pragma unroll
    for (int d=0; d<64; d++) qreg[d] = ap[d];
  }
  float m = -1e30f, l = 0.f;
  float acc[8] = {0,0,0,0,0,0,0,0};
  const int g0 = sp * 980;
  for (int c = 0; c < 8; c++){
    for (int idx = tid; idx < 2048; idx += 320){
      int r = idx >> 4, g = idx & 15;
      int loc = c*128 + r; if (loc > 979) loc = 979;
      int gk = g0 + loc;
      int tk = gk / 3136, nv = gk - tk*3136;
      size_t grow = (size_t)((b*5+tk)*3137 + 1 + nv)*1536 + 512 + h*128 + g*8;
      u16x8 v = *(const u16x8*)(out1 + grow);
      char* dst = (g < 8) ? Ksm : Vsm;
      int seg = g & 7;
      *(u16x8*)(dst + r*128 + ((seg*16) ^ ((r&7)<<4))) = v;
    }
    __syncthreads();
    float s0 = 0.f, s1 = 0.f;
#pragma unroll
    for (int seg=0; seg<8; seg++){
      const int r0 = lane, r1 = 64 + lane;
      u16x8 k0 = *(const u16x8*)(Ksm + r0*128 + ((seg*16) ^ ((r0&7)<<4)));
      u16x8 k1 = *(const u16x8*)(Ksm + r1*128 + ((seg*16) ^ ((r1&7)<<4)));
#pragma unroll
      for (int j=0;j<8;j++){
        s0 += qreg[seg*8+j]*b2f(k0[j]);
        s1 += qreg[seg*8+j]*b2f(k1[j]);
      }
    }
    s0 *= 0.125f; s1 *= 0.125f;
    const int locbase = c*128;
    if (locbase + lane >= 980)      s0 = -1e30f;
    if (locbase + 64 + lane >= 980) s1 = -1e30f;
    float cmax = wred_max(fmaxf(s0, s1));
    float mn = fmaxf(m, cmax);
    float resc = __expf(m - mn);
    float p0 = (s0 > -1e29f) ? __expf(s0 - mn) : 0.f;
    float p1 = (s1 > -1e29f) ? __expf(s1 - mn) : 0.f;
    l = l*resc + wred_sum(p0 + p1);
#pragma unroll
    for (int j=0;j<8;j++) acc[j] *= resc;
    const int g = lane >> 3, cc = lane & 7;
#pragma unroll
    for (int i=0;i<16;i++){
      int k = i*8 + g;
      u16x8 vv = *(const u16x8*)(Vsm + k*128 + ((cc*16) ^ ((k&7)<<4)));
      float p = (i < 8) ? __shfl(p0, k) : __shfl(p1, k-64);
#pragma unroll
      for (int j=0;j<8;j++) acc[j] += p*b2f(vv[j]);
    }
    m = mn;
    __syncthreads();
  }
#pragma unroll
  for (int j=0;j<8;j++){
    float v = acc[j];
    v += __shfl_xor(v, 8); v += __shfl_xor(v, 16); v += __shfl_xor(v, 32);
    acc[j] = v;
  }
  const int base = (bh*16 + sp)*5 + q;
  if (lane == 0){ pm[base] = m; pl[base] = l; }
  if (lane < 8){
    float* pa = pacc + (size_t)base*64 + lane*8;
#pragma unroll
    for (int j=0;j<8;j++) pa[j] = acc[j];
  }
}

// ---- frame attention (k=5)+mask -> unmasked v rows of IN; masked rows -> out=b_out;
//      fused split-K combine -> agent rows of IN ----
__global__ __launch_bounds__(256) void k_attn_frame(
    const u16* __restrict__ out1, const float* __restrict__ aqkv,
    const float* __restrict__ mask, const float* __restrict__ pm,
    const float* __restrict__ pl, const float* __restrict__ pacc,
    u16* __restrict__ IN, float* __restrict__ out, const float* __restrict__ b_out)
{
  const int bid = blockIdx.x, tid = threadIdx.x;
  if (bid < 3920){
    __shared__ float Ka[5][8][68];
    __shared__ float Va[5][8][68];
    const int b = bid / 490, bx = bid % 490;
    for (int i = tid; i < 2560; i += 256){
      int t = i >> 9, rem = i & 511, hh = rem >> 6, d = rem & 63;
      const float* src = aqkv + (size_t)(b*5+t)*1536;
      Ka[t][hh][d] = src[512 + hh*64 + d];
      Va[t][hh][d] = src[1024 + hh*64 + d];
    }
    __syncthreads();
    const int task = bx*256 + tid;
    const int h = task & 7, rl = task >> 3;
    const int f = rl / 3136, nv = rl - f*3136;
    const int bt = b*5 + f;
    const size_t r1 = (size_t)bt*3137 + 1 + nv;
    const float mraw = mask[(size_t)bt*3136 + nv];
    if (mraw == 0.f){
      // masked row: output = exactly b_out (fused biasfill)
      const float4* bp = (const float4*)(b_out + h*64);
      float4* of = (float4*)(out + r1*512 + h*64);
#pragma unroll
      for (int i=0;i<16;i++) of[i] = bp[i];
    } else {
      const u16* qp = out1 + r1*1536 + h*64;
      float qf[64];
#pragma unroll
      for (int sg=0; sg<8; sg++){
        u16x8 v = *(const u16x8*)(qp + sg*8);
#pragma unroll
        for (int j=0;j<8;j++) qf[sg*8+j] = b2f(v[j]);
      }
      float sd[5];
#pragma unroll
      for (int t=0;t<5;t++){
        float s = 0.f;
#pragma unroll
        for (int d=0;d<64;d++) s += qf[d]*Ka[t][h][d];
        sd[t] = s*0.125f;
      }
      float mx = sd[0];
#pragma unroll
      for (int t=1;t<5;t++) mx = fmaxf(mx, sd[t]);
      float p[5], ps = 0.f;
#pragma unroll
      for (int t=0;t<5;t++){ p[t] = __expf(sd[t]-mx); ps += p[t]; }
      const float mv = mraw / ps;
      u16* op = IN + r1*512 + h*64;
#pragma unroll
      for (int sg=0; sg<8; sg++){
        u16x8 o;
#pragma unroll
        for (int j=0;j<8;j++){
          const int d = sg*8+j;
          float v = 0.f;
#pragma unroll
          for (int t=0;t<5;t++) v += p[t]*Va[t][h][d];
          o[j] = f2b(v*mv);
        }
        *(u16x8*)(op + sg*8) = o;
      }
    }
  } else {
    const int id = (bid - 3920)*4 + (tid >> 6);
    const int d = tid & 63;
    const int q = id % 5, t2 = id / 5;
    const int h = t2 & 7, b = t2 >> 3;
    const int bh = b*8 + h;
    float ms = -1e30f;
#pragma unroll
    for (int s2=0;s2<16;s2++) ms = fmaxf(ms, pm[(bh*16+s2)*5+q]);
    float L = 0.f, o = 0.f;
#pragma unroll
    for (int s2=0;s2<16;s2++){
      int base = (bh*16+s2)*5+q;
      float w = __expf(pm[base]-ms);
      L += w*pl[base];
      o += w*pacc[(size_t)base*64 + d];
    }
    IN[(size_t)(b*5+q)*3137*512 + h*64 + d] = f2b(o / L);
  }
}

extern "C" void kernel_launch(void* const* d_in, const int* in_sizes, int n_in,
                              void* d_out, int out_size, void* d_ws, size_t ws_size,
                              hipStream_t stream)
{
  const float* x      = (const float*)d_in[0];
  const float* mask   = (const float*)d_in[1];
  const float* w_vq   = (const float*)d_in[2];
  const float* w_vkv  = (const float*)d_in[3];
  const float* w_aqkv = (const float*)d_in[4];
  const float* w_out  = (const float*)d_in[5];
  const float* b_out  = (const float*)d_in[6];
  float* out = (float*)d_out;
  char* ws = (char*)d_ws;

  constexpr size_t MR = 125480;                          // 40*3137
  constexpr size_t OFF_XB   = 0;                         // M x 512 bf16 (GEMM1 A; later IN)
  constexpr size_t OFF_OUT1 = OFF_XB + MR*512*2;         // M x 1536 bf16 (vq | per-head kv)
  constexpr size_t OFF_W1T  = OFF_OUT1 + MR*1536*2;      // 1536x512 bf16 (permuted cols)
  constexpr size_t OFF_WOT  = OFF_W1T + 1536*512*2;      // 512x512 bf16
  constexpr size_t OFF_AQKV = OFF_WOT + 512*512*2;       // 40x1536 f32
  constexpr size_t OFF_PM   = OFF_AQKV + 40*1536*4;      // 5120 f32
  constexpr size_t OFF_PL   = OFF_PM + 5120*4;           // 5120 f32
  constexpr size_t OFF_PACC = OFF_PL + 5120*4;           // 5120*64 f32
  constexpr size_t OFF_ROWS = OFF_PACC + 5120*64*4;      // 125480 u32
  constexpr size_t OFF_CNT  = OFF_ROWS + MR*4;           // 1 u32

  u16* Xb     = (u16*)(ws + OFF_XB);
  u16* out1   = (u16*)(ws + OFF_OUT1);
  u16* W1T    = (u16*)(ws + OFF_W1T);
  u16* WoutT  = (u16*)(ws + OFF_WOT);
  float* aqkv = (float*)(ws + OFF_AQKV);
  float* pm   = (float*)(ws + OFF_PM);
  float* pl   = (float*)(ws + OFF_PL);
  float* pacc = (float*)(ws + OFF_PACC);
  u32* rows   = (u32*)(ws + OFF_ROWS);
  u32* cnt    = (u32*)(ws + OFF_CNT);

  // zero the list counter (stream-ordered, graph-capture-safe)
  hipMemsetAsync(cnt, 0, 4, stream);
  // cast / weight prep / agent qkv / compacted row list
  k_pre<<<6875, 256, 0, stream>>>(x, w_vq, w_vkv, w_out, w_aqkv, mask,
                                  Xb, W1T, WoutT, aqkv, rows, cnt);
  // merged GEMM1: KV (dense, 1964 blocks) + VQ (gathered, 982 blocks)
  k_gemm8p<3><<<2946, 512, 0, stream>>>(Xb, W1T, (int)MR, 1964, 512, 1536,
                                        out1, nullptr, nullptr, rows, cnt);
  k_attn_agent<<<1024, 320, 0, stream>>>(out1, aqkv, pm, pl, pacc);
  k_attn_frame<<<4000, 256, 0, stream>>>(out1, aqkv, mask, pm, pl, pacc,
                                         Xb, out, b_out);
  // output projection: compacted rows only (masked rows = b_out via attn_frame)
  k_gemm8p<2><<<982, 512, 0, stream>>>(Xb, WoutT, (int)MR, 0, 512, 512,
                                       nullptr, out, b_out, rows, cnt);
}

// Round 21
// 733.589 us; speedup vs baseline: 1.0181x; 1.0181x over previous
//
#include <hip/hip_runtime.h>

typedef unsigned short u16;
typedef unsigned int u32;
typedef __attribute__((ext_vector_type(8))) u16 u16x8;
typedef __attribute__((ext_vector_type(8))) __bf16 bf16x8;
typedef __attribute__((ext_vector_type(4))) float f32x4;

__device__ __forceinline__ float b2f(u16 u){ return __uint_as_float(((u32)u)<<16); }
__device__ __forceinline__ u16 f2b(float f){
  u32 b = __float_as_uint(f);
  return (u16)((b + 0x7fffu + ((b>>16)&1u))>>16);
}
__device__ __forceinline__ void gload16(const void* g, void* l){
  __builtin_amdgcn_global_load_lds((__attribute__((address_space(1))) void*)g,
                                   (__attribute__((address_space(3))) void*)l, 16, 0, 0);
}
__device__ __forceinline__ float wred_max(float v){
#pragma unroll
  for (int o=32;o>0;o>>=1) v = fmaxf(v, __shfl_xor(v,o));
  return v;
}
__device__ __forceinline__ float wred_sum(float v){
#pragma unroll
  for (int o=32;o>0;o>>=1) v += __shfl_xor(v,o);
  return v;
}

// ================== FINAL configuration (r19, measured best 735.9us) =========
// Verified wins: XCD-bijective swizzle for dense GEMM (FETCH 512->81MB);
// identity map for gathered GEMMs (prefix range would idle XCDs 4-7, r18);
// W1T col permutation -> out1 = [vq | per-head kv] (dense attn reads, zero
// GEMM cost); mask-driven row compaction of VQ+GEMM2 (~50% rows masked ->
// their outputs are exactly b_out, written by attn_frame's masked branch).
// Falsified (do not reintroduce): nt-stores (2x write amp, r4); routed /
// head-major epilogues (r11/r12); per-lane store branch (r11); frame-attn in
// GEMM epilogue (r10); alt GEMM schedules incl. merged KV+VQ dispatch (r20):
// the ~290us 8-phase structure is the source-level plateau at K=512.
// out1 column order:
//   [0,512)   : vq (original order)   -- computed ONLY for unmasked rows
//   512+h*128 : head h's vk(64)|vv(64) -- all rows (agent attn needs every key)

// ---- fused preprocessing: cast x | weight transposes | agent qkv | row list ----
__global__ void k_pre(const float* __restrict__ x, const float* __restrict__ wvq,
                      const float* __restrict__ wvkv, const float* __restrict__ wout,
                      const float* __restrict__ waqkv, const float* __restrict__ mask,
                      u16* __restrict__ xb, u16* __restrict__ W1T,
                      u16* __restrict__ WoutT, float* __restrict__ aqkv,
                      u32* __restrict__ rowlist, u32* __restrict__ cnt){
  const int bid = blockIdx.x, tid = threadIdx.x;
  if (bid < 2048){
    const int stride = 2048*256;
    for (int i = bid*256 + tid; i < 8030720; i += stride){
      const float4* p = (const float4*)(x + (size_t)i*8);
      float4 a = p[0], b = p[1];
      u16x8 o;
      o[0]=f2b(a.x); o[1]=f2b(a.y); o[2]=f2b(a.z); o[3]=f2b(a.w);
      o[4]=f2b(b.x); o[5]=f2b(b.y); o[6]=f2b(b.z); o[7]=f2b(b.w);
      *(u16x8*)(xb + (size_t)i*8) = o;
    }
  } else if (bid < 6144){
    int id = (bid-2048)*256 + tid;
    if (id < 786432){
      int n = id >> 9, k = id & 511;
      float v;
      if (n < 512){
        v = wvq[k*512 + n];
      } else {
        int j = n - 512, h = j >> 7, r = j & 127;
        int c2 = (r < 64) ? (h*64 + r) : (512 + h*64 + (r - 64));   // vk | vv
        v = wvkv[k*1024 + c2];
      }
      W1T[id] = f2b(v);
    } else {
      int j = id - 786432;
      int n = j >> 9, k = j & 511;
      WoutT[j] = f2b(wout[k*512 + n]);
    }
  } else if (bid < 6384){
    int id = (bid-6144)*256 + tid;
    int bt = id / 1536, c = id % 1536;
    const float* xr = x + (size_t)bt*3137*512;
    float s = 0.f;
    for (int k=0;k<512;k++) s += xr[k]*waqkv[k*1536+c];
    aqkv[id] = s;
  } else {
    // compacted row list: wave-aggregated ballot append
    int j = (bid-6384)*256 + tid;    // [0, 125696)
    bool pred = false; u32 row = 0;
    if (j < 125440){
      int bt = j / 3136, nv = j - bt*3136;
      pred = (mask[j] != 0.f);
      row = (u32)(bt*3137 + 1 + nv);
    } else if (j < 125480){
      pred = true;                   // 40 agent rows always included
      row = (u32)((j - 125440) * 3137);
    }
    unsigned long long bal = __ballot(pred);
    const int lane = tid & 63;
    u32 base = 0;
    if (lane == 0 && bal) base = atomicAdd(cnt, (u32)__popcll(bal));
    base = __shfl(base, 0);
    if (pred){
      int pos = __popcll(bal & ((1ull << lane) - 1ull));
      rowlist[base + pos] = row;
    }
  }
}

// ======== 256x256 GEMM, 8-phase schedule (m201 port, r17/r19-verified) ========
// MODE 0: dense rows, bf16 out at Cb[row*ldc + coff + col]      (KV part)
// MODE 1: gathered rows (rowlist, M=*cntp), bf16 out            (VQ part)
// MODE 2: gathered rows, f32 + bias out                         (GEMM2)
// XCD swizzle ONLY for MODE 0 (dense): for gathered GEMMs the active work
// range is a prefix -> m204's contiguous-chunk mapping idles XCDs 4-7
// (measured r18: VQ/GEMM2 ~2x slow). Identity mapping round-robins instead.
template<int MODE>
__global__ __launch_bounds__(512, 2) void k_gemm8p(
    const u16* __restrict__ A, const u16* __restrict__ BT,
    int M, int N, int K, int NX, int ldc, int coff,
    u16* __restrict__ Cb, float* __restrict__ Cf, const float* __restrict__ bias,
    const u32* __restrict__ rowlist, const u32* __restrict__ cntp)
{
  __shared__ __align__(16) char Ls[131072];
  char* LA = Ls;             // + d*32768 + h*16384
  char* LB = Ls + 65536;
  const int tid = threadIdx.x;
  const int wid = tid >> 6, lane = tid & 63;
  const int wm = wid >> 2, wn = wid & 3;
  int Mg = M;
  if (MODE != 0) Mg = (int)*cntp;
  int work;
  if (MODE == 0){
    // XCD-bijective swizzle (m204), n-fast work order
    const int nwg = gridDim.x, orig = blockIdx.x;
    const int q8 = nwg >> 3, r8 = nwg & 7;
    const int xc = orig & 7, sl = orig >> 3;
    work = (xc < r8 ? xc*(q8+1) : r8*(q8+1) + (xc-r8)*q8) + sl;
  } else {
    work = blockIdx.x;               // identity: active prefix spreads over XCDs
  }
  const int m0 = (work / NX) * 256, n0 = (work % NX) * 256;
  if (MODE != 0 && m0 >= Mg) return;   // past compacted range
  const size_t K2 = (size_t)K * 2;
  const char* Ab = (const char*)A;
  const char* Bb = (const char*)BT;
  size_t asrch[2], bsrch[2];
#pragma unroll
  for (int h=0; h<2; h++){
    int ra = m0 + h*128 + wid*16 + (lane & 15);
    if (ra >= Mg) ra = Mg - 1;                     // clamp partial tail
    size_t arow = (MODE == 0) ? (size_t)ra : (size_t)rowlist[ra];
    asrch[h] = arow * K2 + ((lane >> 4) << 4);
    bsrch[h] = (size_t)(n0 + h*128 + wid*16 + (lane & 15)) * K2 + ((lane >> 4) << 4);
  }
  const int sd0 = wid*2048;                        // wave-uniform LDS dest base

#define STG_A(d,h,kt) { size_t ko = (size_t)(kt)*128; \
    gload16(Ab + asrch[h] + ko,      LA + (d)*32768 + (h)*16384 + sd0); \
    gload16(Ab + asrch[h] + ko + 64, LA + (d)*32768 + (h)*16384 + sd0 + 1024); }
#define STG_B(d,h,kt) { size_t ko = (size_t)(kt)*128; \
    gload16(Bb + bsrch[h] + ko,      LB + (d)*32768 + (h)*16384 + sd0); \
    gload16(Bb + bsrch[h] + ko + 64, LB + (d)*32768 + (h)*16384 + sd0 + 1024); }

  bf16x8 afr[4][2], bfr[2][2];
#define RD_A(d,QM) { const char* ab_ = LA + (d)*32768 + (QM)*16384 + wm*8192 + lane*16; \
    _Pragma("unroll") for (int fm=0; fm<4; fm++){ \
      afr[fm][0] = *(const bf16x8*)(ab_ + fm*2048); \
      afr[fm][1] = *(const bf16x8*)(ab_ + fm*2048 + 1024); } }
#define RD_B(d,QN) { const char* bb_ = LB + (d)*32768 + (QN)*16384 + wn*4096 + lane*16; \
    _Pragma("unroll") for (int fn=0; fn<2; fn++){ \
      bfr[fn][0] = *(const bf16x8*)(bb_ + fn*2048); \
      bfr[fn][1] = *(const bf16x8*)(bb_ + fn*2048 + 1024); } }

  f32x4 acc[8][4] = {};
#define MFMA16(QM,QN) { \
    _Pragma("unroll") for (int fm=0; fm<4; fm++){ \
      _Pragma("unroll") for (int fn=0; fn<2; fn++){ \
        acc[(QM)*4+fm][(QN)*2+fn] = __builtin_amdgcn_mfma_f32_16x16x32_bf16( \
            afr[fm][0], bfr[fn][0], acc[(QM)*4+fm][(QN)*2+fn], 0,0,0); \
        acc[(QM)*4+fm][(QN)*2+fn] = __builtin_amdgcn_mfma_f32_16x16x32_bf16( \
            afr[fm][1], bfr[fn][1], acc[(QM)*4+fm][(QN)*2+fn], 0,0,0); } } }

#define PH_MID(QM,QN) \
    __builtin_amdgcn_sched_barrier(0); \
    __builtin_amdgcn_s_barrier(); \
    asm volatile("s_waitcnt lgkmcnt(0)" ::: "memory"); \
    __builtin_amdgcn_sched_barrier(0); \
    __builtin_amdgcn_s_setprio(1); \
    MFMA16(QM,QN) \
    __builtin_amdgcn_s_setprio(0); \
    __builtin_amdgcn_sched_barrier(0);
#define BAR __builtin_amdgcn_s_barrier()

  const int NI = K >> 7;                           // K=512 -> 4 iterations
  STG_A(0,0,0) STG_B(0,1,0) STG_A(0,1,0) STG_B(0,0,0) STG_A(1,0,1) STG_B(1,1,1)
  asm volatile("s_waitcnt vmcnt(4)" ::: "memory");
  BAR;

  for (int it = 0; it < NI; ++it){
    const int t1 = 2*it + 1, t2 = 2*it + 2, t3 = 2*it + 3;
    const bool more = (it + 1 < NI);
    RD_A(0,0) RD_B(0,0) STG_A(1,1,t1)
    PH_MID(0,0) BAR;
    RD_B(0,1) STG_B(1,0,t1)
    PH_MID(0,1) BAR;
    RD_A(0,1) if (more){ STG_A(0,0,t2) }
    PH_MID(1,1) BAR;
    RD_B(0,0) if (more){ STG_B(0,1,t2) }
    PH_MID(1,0)
    if (more) { asm volatile("s_waitcnt vmcnt(4)" ::: "memory"); }
    else      { asm volatile("s_waitcnt vmcnt(0)" ::: "memory"); }
    BAR;
    RD_A(1,0) RD_B(1,0) if (more){ STG_A(0,1,t2) }
    PH_MID(0,0) BAR;
    RD_B(1,1) if (more){ STG_B(0,0,t2) }
    PH_MID(0,1) BAR;
    RD_A(1,1) if (more){ STG_A(1,0,t3) }
    PH_MID(1,1) BAR;
    RD_B(1,0) if (more){ STG_B(1,1,t3) }
    PH_MID(1,0)
    if (more) { asm volatile("s_waitcnt vmcnt(4)" ::: "memory"); }
    BAR;
  }
#undef STG_A
#undef STG_B
#undef RD_A
#undef RD_B
#undef MFMA16
#undef PH_MID
#undef BAR
  // epilogue: plain scalar stores (nt = 2x write amp r4; routed epilogues r11/r12)
  const bool full = (m0 + 256 <= Mg);
  if (full){
#pragma unroll
    for (int mi=0; mi<8; mi++){
      const int rb = m0 + (mi>>2)*128 + wm*64 + (mi&3)*16 + ((lane>>4)<<2);
#pragma unroll
      for (int rg=0; rg<4; rg++){
        const int r = rb + rg;
        const size_t orow = (MODE == 0) ? (size_t)r : (size_t)rowlist[r];
#pragma unroll
        for (int ni=0; ni<4; ni++){
          const int col = n0 + (ni>>1)*128 + wn*32 + (ni&1)*16 + (lane&15);
          float v = acc[mi][ni][rg];
          if (MODE == 2) Cf[orow*(size_t)ldc + col] = v + bias[col];
          else           Cb[orow*(size_t)ldc + coff + col] = f2b(v);
        }
      }
    }
  } else {
#pragma unroll
    for (int mi=0; mi<8; mi++){
      const int rb = m0 + (mi>>2)*128 + wm*64 + (mi&3)*16 + ((lane>>4)<<2);
#pragma unroll
      for (int rg=0; rg<4; rg++){
        const int r = rb + rg;
        if (r < Mg){
          const size_t orow = (MODE == 0) ? (size_t)r : (size_t)rowlist[r];
#pragma unroll
          for (int ni=0; ni<4; ni++){
            const int col = n0 + (ni>>1)*128 + wn*32 + (ni&1)*16 + (lane&15);
            float v = acc[mi][ni][rg];
            if (MODE == 2) Cf[orow*(size_t)ldc + col] = v + bias[col];
            else           Cb[orow*(size_t)ldc + coff + col] = f2b(v);
          }
        }
      }
    }
  }
}

// ---------------- agent attention: softmax over 15680 keys, split-K=16 ----------------
__global__ __launch_bounds__(320) void k_attn_agent(
    const u16* __restrict__ out1, const float* __restrict__ aqkv,
    float* __restrict__ pm, float* __restrict__ pl, float* __restrict__ pacc)
{
  __shared__ __align__(16) char Ksm[16384];   // 128 keys x 64 bf16, XOR-swizzled
  __shared__ __align__(16) char Vsm[16384];
  const int bid = blockIdx.x;
  const int sp = bid & 15, bh = bid >> 4, b = bh >> 3, h = bh & 7;
  const int tid = threadIdx.x, wid = tid >> 6, lane = tid & 63;
  const int q = wid;
  float qreg[64];
  {
    const float* ap = aqkv + ((size_t)(b*5+q)*1536 + h*64);
#pragma unroll
    for (int d=0; d<64; d++) qreg[d] = ap[d];
  }
  float m = -1e30f, l = 0.f;
  float acc[8] = {0,0,0,0,0,0,0,0};
  const int g0 = sp * 980;
  for (int c = 0; c < 8; c++){
    for (int idx = tid; idx < 2048; idx += 320){
      int r = idx >> 4, g = idx & 15;
      int loc = c*128 + r; if (loc > 979) loc = 979;
      int gk = g0 + loc;
      int tk = gk / 3136, nv = gk - tk*3136;
      size_t grow = (size_t)((b*5+tk)*3137 + 1 + nv)*1536 + 512 + h*128 + g*8;
      u16x8 v = *(const u16x8*)(out1 + grow);
      char* dst = (g < 8) ? Ksm : Vsm;
      int seg = g & 7;
      *(u16x8*)(dst + r*128 + ((seg*16) ^ ((r&7)<<4))) = v;
    }
    __syncthreads();
    float s0 = 0.f, s1 = 0.f;
#pragma unroll
    for (int seg=0; seg<8; seg++){
      const int r0 = lane, r1 = 64 + lane;
      u16x8 k0 = *(const u16x8*)(Ksm + r0*128 + ((seg*16) ^ ((r0&7)<<4)));
      u16x8 k1 = *(const u16x8*)(Ksm + r1*128 + ((seg*16) ^ ((r1&7)<<4)));
#pragma unroll
      for (int j=0;j<8;j++){
        s0 += qreg[seg*8+j]*b2f(k0[j]);
        s1 += qreg[seg*8+j]*b2f(k1[j]);
      }
    }
    s0 *= 0.125f; s1 *= 0.125f;
    const int locbase = c*128;
    if (locbase + lane >= 980)      s0 = -1e30f;
    if (locbase + 64 + lane >= 980) s1 = -1e30f;
    float cmax = wred_max(fmaxf(s0, s1));
    float mn = fmaxf(m, cmax);
    float resc = __expf(m - mn);
    float p0 = (s0 > -1e29f) ? __expf(s0 - mn) : 0.f;
    float p1 = (s1 > -1e29f) ? __expf(s1 - mn) : 0.f;
    l = l*resc + wred_sum(p0 + p1);
#pragma unroll
    for (int j=0;j<8;j++) acc[j] *= resc;
    const int g = lane >> 3, cc = lane & 7;
#pragma unroll
    for (int i=0;i<16;i++){
      int k = i*8 + g;
      u16x8 vv = *(const u16x8*)(Vsm + k*128 + ((cc*16) ^ ((k&7)<<4)));
      float p = (i < 8) ? __shfl(p0, k) : __shfl(p1, k-64);
#pragma unroll
      for (int j=0;j<8;j++) acc[j] += p*b2f(vv[j]);
    }
    m = mn;
    __syncthreads();
  }
#pragma unroll
  for (int j=0;j<8;j++){
    float v = acc[j];
    v += __shfl_xor(v, 8); v += __shfl_xor(v, 16); v += __shfl_xor(v, 32);
    acc[j] = v;
  }
  const int base = (bh*16 + sp)*5 + q;
  if (lane == 0){ pm[base] = m; pl[base] = l; }
  if (lane < 8){
    float* pa = pacc + (size_t)base*64 + lane*8;
#pragma unroll
    for (int j=0;j<8;j++) pa[j] = acc[j];
  }
}

// ---- frame attention (k=5)+mask -> unmasked v rows of IN; masked rows -> out=b_out;
//      fused split-K combine -> agent rows of IN ----
__global__ __launch_bounds__(256) void k_attn_frame(
    const u16* __restrict__ out1, const float* __restrict__ aqkv,
    const float* __restrict__ mask, const float* __restrict__ pm,
    const float* __restrict__ pl, const float* __restrict__ pacc,
    u16* __restrict__ IN, float* __restrict__ out, const float* __restrict__ b_out)
{
  const int bid = blockIdx.x, tid = threadIdx.x;
  if (bid < 3920){
    __shared__ float Ka[5][8][68];
    __shared__ float Va[5][8][68];
    const int b = bid / 490, bx = bid % 490;
    for (int i = tid; i < 2560; i += 256){
      int t = i >> 9, rem = i & 511, hh = rem >> 6, d = rem & 63;
      const float* src = aqkv + (size_t)(b*5+t)*1536;
      Ka[t][hh][d] = src[512 + hh*64 + d];
      Va[t][hh][d] = src[1024 + hh*64 + d];
    }
    __syncthreads();
    const int task = bx*256 + tid;
    const int h = task & 7, rl = task >> 3;
    const int f = rl / 3136, nv = rl - f*3136;
    const int bt = b*5 + f;
    const size_t r1 = (size_t)bt*3137 + 1 + nv;
    const float mraw = mask[(size_t)bt*3136 + nv];
    if (mraw == 0.f){
      // masked row: output = exactly b_out (fused biasfill)
      const float4* bp = (const float4*)(b_out + h*64);
      float4* of = (float4*)(out + r1*512 + h*64);
#pragma unroll
      for (int i=0;i<16;i++) of[i] = bp[i];
    } else {
      const u16* qp = out1 + r1*1536 + h*64;
      float qf[64];
#pragma unroll
      for (int sg=0; sg<8; sg++){
        u16x8 v = *(const u16x8*)(qp + sg*8);
#pragma unroll
        for (int j=0;j<8;j++) qf[sg*8+j] = b2f(v[j]);
      }
      float sd[5];
#pragma unroll
      for (int t=0;t<5;t++){
        float s = 0.f;
#pragma unroll
        for (int d=0;d<64;d++) s += qf[d]*Ka[t][h][d];
        sd[t] = s*0.125f;
      }
      float mx = sd[0];
#pragma unroll
      for (int t=1;t<5;t++) mx = fmaxf(mx, sd[t]);
      float p[5], ps = 0.f;
#pragma unroll
      for (int t=0;t<5;t++){ p[t] = __expf(sd[t]-mx); ps += p[t]; }
      const float mv = mraw / ps;
      u16* op = IN + r1*512 + h*64;
#pragma unroll
      for (int sg=0; sg<8; sg++){
        u16x8 o;
#pragma unroll
        for (int j=0;j<8;j++){
          const int d = sg*8+j;
          float v = 0.f;
#pragma unroll
          for (int t=0;t<5;t++) v += p[t]*Va[t][h][d];
          o[j] = f2b(v*mv);
        }
        *(u16x8*)(op + sg*8) = o;
      }
    }
  } else {
    const int id = (bid - 3920)*4 + (tid >> 6);
    const int d = tid & 63;
    const int q = id % 5, t2 = id / 5;
    const int h = t2 & 7, b = t2 >> 3;
    const int bh = b*8 + h;
    float ms = -1e30f;
#pragma unroll
    for (int s2=0;s2<16;s2++) ms = fmaxf(ms, pm[(bh*16+s2)*5+q]);
    float L = 0.f, o = 0.f;
#pragma unroll
    for (int s2=0;s2<16;s2++){
      int base = (bh*16+s2)*5+q;
      float w = __expf(pm[base]-ms);
      L += w*pl[base];
      o += w*pacc[(size_t)base*64 + d];
    }
    IN[(size_t)(b*5+q)*3137*512 + h*64 + d] = f2b(o / L);
  }
}

extern "C" void kernel_launch(void* const* d_in, const int* in_sizes, int n_in,
                              void* d_out, int out_size, void* d_ws, size_t ws_size,
                              hipStream_t stream)
{
  const float* x      = (const float*)d_in[0];
  const float* mask   = (const float*)d_in[1];
  const float* w_vq   = (const float*)d_in[2];
  const float* w_vkv  = (const float*)d_in[3];
  const float* w_aqkv = (const float*)d_in[4];
  const float* w_out  = (const float*)d_in[5];
  const float* b_out  = (const float*)d_in[6];
  float* out = (float*)d_out;
  char* ws = (char*)d_ws;

  constexpr size_t MR = 125480;                          // 40*3137
  constexpr size_t OFF_XB   = 0;                         // M x 512 bf16 (GEMM1 A; later IN)
  constexpr size_t OFF_OUT1 = OFF_XB + MR*512*2;         // M x 1536 bf16 (vq | per-head kv)
  constexpr size_t OFF_W1T  = OFF_OUT1 + MR*1536*2;      // 1536x512 bf16 (permuted cols)
  constexpr size_t OFF_WOT  = OFF_W1T + 1536*512*2;      // 512x512 bf16
  constexpr size_t OFF_AQKV = OFF_WOT + 512*512*2;       // 40x1536 f32
  constexpr size_t OFF_PM   = OFF_AQKV + 40*1536*4;      // 5120 f32
  constexpr size_t OFF_PL   = OFF_PM + 5120*4;           // 5120 f32
  constexpr size_t OFF_PACC = OFF_PL + 5120*4;           // 5120*64 f32
  constexpr size_t OFF_ROWS = OFF_PACC + 5120*64*4;      // 125480 u32
  constexpr size_t OFF_CNT  = OFF_ROWS + MR*4;           // 1 u32

  u16* Xb     = (u16*)(ws + OFF_XB);
  u16* out1   = (u16*)(ws + OFF_OUT1);
  u16* W1T    = (u16*)(ws + OFF_W1T);
  u16* WoutT  = (u16*)(ws + OFF_WOT);
  float* aqkv = (float*)(ws + OFF_AQKV);
  float* pm   = (float*)(ws + OFF_PM);
  float* pl   = (float*)(ws + OFF_PL);
  float* pacc = (float*)(ws + OFF_PACC);
  u32* rows   = (u32*)(ws + OFF_ROWS);
  u32* cnt    = (u32*)(ws + OFF_CNT);

  // zero the list counter (stream-ordered, graph-capture-safe)
  hipMemsetAsync(cnt, 0, 4, stream);
  // cast / weight prep / agent qkv / compacted row list
  k_pre<<<6875, 256, 0, stream>>>(x, w_vq, w_vkv, w_out, w_aqkv, mask,
                                  Xb, W1T, WoutT, aqkv, rows, cnt);
  // KV projection: all rows, N=1024 (out1 cols 512..1536), XCD-swizzled
  k_gemm8p<0><<<1964, 512, 0, stream>>>(Xb, W1T + 512*512, (int)MR, 1024, 512, 4,
                                        1536, 512, out1, nullptr, nullptr,
                                        nullptr, nullptr);
  // VQ projection: compacted rows only, N=512 (out1 cols 0..512), identity map
  k_gemm8p<1><<<982, 512, 0, stream>>>(Xb, W1T, (int)MR, 512, 512, 2,
                                       1536, 0, out1, nullptr, nullptr,
                                       rows, cnt);
  k_attn_agent<<<1024, 320, 0, stream>>>(out1, aqkv, pm, pl, pacc);
  k_attn_frame<<<4000, 256, 0, stream>>>(out1, aqkv, mask, pm, pl, pacc,
                                         Xb, out, b_out);
  // output projection: compacted rows only (masked rows = b_out via attn_frame)
  k_gemm8p<2><<<982, 512, 0, stream>>>(Xb, WoutT, (int)MR, 512, 512, 2,
                                       512, 0, nullptr, out, b_out,
                                       rows, cnt);
}